// Round 2
// baseline (118.428 us; speedup 1.0000x reference)
//
#include <hip/hip_runtime.h>
#include <stdint.h>

#define NAC 147456   // 128*128*9
#define NGT 64
#define NB  8
#define APT 3        // anchors per thread in k1 — measured optimum (round 8)
#define BLK 256
#define GX  (NAC / (BLK * APT))   // 192 -> grid 192x8 = 1536 blocks = 6/CU exact

// ---------------- Threefry-2x32 (JAX-compatible, 20 rounds) ----------------
__host__ __device__ static inline uint32_t tf_rotl(uint32_t x, uint32_t d) {
  return (x << d) | (x >> (32u - d));
}

__host__ __device__ static inline void threefry2x32(
    uint32_t k0, uint32_t k1, uint32_t x0, uint32_t x1,
    uint32_t* o0, uint32_t* o1)
{
  const uint32_t ks2 = k0 ^ k1 ^ 0x1BD11BDAu;
  x0 += k0; x1 += k1;
#define TFR(r) { x0 += x1; x1 = tf_rotl(x1, (r)); x1 ^= x0; }
  TFR(13u) TFR(15u) TFR(26u) TFR(6u)   x0 += k1;  x1 += ks2 + 1u;
  TFR(17u) TFR(29u) TFR(16u) TFR(24u)  x0 += ks2; x1 += k0 + 2u;
  TFR(13u) TFR(15u) TFR(26u) TFR(6u)   x0 += k0;  x1 += k1 + 3u;
  TFR(17u) TFR(29u) TFR(16u) TFR(24u)  x0 += k1;  x1 += ks2 + 4u;
  TFR(13u) TFR(15u) TFR(26u) TFR(6u)   x0 += ks2; x1 += k0 + 5u;
#undef TFR
  *o0 = x0; *o1 = x1;
}

__device__ static inline void bbox2delta_store(
    const float4& a, const float4& g, float* dst)
{
  const float wr  = a.w - a.y,          hr  = a.z - a.x;
  const float xcr = a.y + 0.5f * wr,    ycr = a.x + 0.5f * hr;
  const float wrc = fmaxf(wr, 1e-5f),   hrc = fmaxf(hr, 1e-5f);
  const float wl  = g.w - g.y,          hl  = g.z - g.x;
  const float xcl = g.y + 0.5f * wl,    ycl = g.x + 0.5f * hl;
  float4 r;
  r.x = fminf(fmaxf((xcl - xcr) / wrc, -10.0f), 10.0f);
  r.y = fminf(fmaxf((ycl - ycr) / hrc, -10.0f), 10.0f);
  r.z = fminf(fmaxf(__logf(wl / wrc),  -10.0f), 10.0f);
  r.w = fminf(fmaxf(__logf(hl / hrc),  -10.0f), 10.0f);
  *reinterpret_cast<float4*>(dst) = r;
}

// ---------------- Kernel 1: IoU argmax + proposals + flags + block count -----
// Round-11 changes (counters: 43.3us @ 81% VALUBusy = ~36 emitted VALU/IoU
// for a ~18-op source loop => pressure/operand bloat, VGPR squeezed to 48):
//  (a) Compare simplification. With S=areaA+ga, x=inter:
//        x_n/(S_n-x_n+e) > x_b/(S_b-x_b+e)  <=>  x_n*(S_b+e) > x_b*(S_n+e)
//      (x_n*x_b cancels). Track (num, T=S+e): per-iter den calc
//      (add+sub+add) collapses to ONE add, T_j = areaA + gae_j with
//      gae = ga+EPS precomputed per j. 18 -> 16 source ops/IoU.
//  (b) GT box components via SGPRs: g is wave-uniform, so load it from
//      GLOBAL with a uniform index -> hipcc emits s_load_dwordx4. Frees
//      ~16 loop-carried VGPRs and drops the per-j ds_read_b128 (only a
//      ds_read_b32 of gae remains). Each v_min/v_max reads 1 SGPR (legal).
// pos threshold stays BIT-IDENTICAL: epilogue recomputes
// den = ((areaA + garea[bidx]) - num) + e in the reference rounding order
// and does ONE IEEE div per anchor (3/thread).
// init (num=0, T=1) keeps "update iff inter>0" first-iter semantics
// (all-zero-overlap anchors -> bidx=0), matching jnp.argmax first-max.
// APT=3 => 1536 blocks = exactly 6 blocks/CU (uniform, no straggler tail).
// NO min-waves launch bound (round 7: register cap spills, +30MB scratch).
template <bool USE_FLAGS>
__global__ __launch_bounds__(BLK) void k1_classify(
    const float* __restrict__ anchors,
    const float* __restrict__ gt,
    const float* __restrict__ deltas,
    float* __restrict__ out,
    int* __restrict__ cnt_blk,          // USE_FLAGS: [NB*GX]; else counts[NB]
    unsigned char* __restrict__ flags)
{
  __shared__ float garea[NGT];   // ga_j   (exact, for epilogue den)
  __shared__ float gae[NGT];     // ga_j + EPS (for T_j in compare)
  __shared__ int   s_cnt;
  const int b   = blockIdx.y;
  const int tid = threadIdx.x;

  if (tid == 0) s_cnt = 0;
  if (tid < NGT) {
    float4 g = reinterpret_cast<const float4*>(gt)[b * NGT + tid];
    const float ga = fmaxf(g.z - g.x, 0.0f) * fmaxf(g.w - g.y, 0.0f);
    garea[tid] = ga;
    gae[tid]   = ga + 1e-5f;
  }
  __syncthreads();

  const float4* __restrict__ gtrow = reinterpret_cast<const float4*>(gt) + b * NGT;
  const int base = blockIdx.x * (BLK * APT) + tid;

  float4 a[APT];
  float  areaA[APT], num[APT], Tb[APT];
  int    bidx[APT];
#pragma unroll
  for (int t = 0; t < APT; ++t) {
    a[t] = reinterpret_cast<const float4*>(anchors)[base + t * BLK];
    areaA[t] = fmaxf(a[t].z - a[t].x, 0.0f) * fmaxf(a[t].w - a[t].y, 0.0f);
    num[t]  = 0.0f;   // incumbent inter
    Tb[t]   = 1.0f;   // incumbent S+e; any >0 gives "update iff inter>0" init
    bidx[t] = 0;
  }

#pragma unroll 4
  for (int j = 0; j < NGT; ++j) {
    const float4 g  = gtrow[j];   // uniform index -> s_load_dwordx4 (SGPRs)
    const float  te = gae[j];     // ds_read_b32
#pragma unroll
    for (int t = 0; t < APT; ++t) {
      float yi = fmaxf(a[t].x, g.x);
      float xi = fmaxf(a[t].y, g.y);
      float ya = fminf(a[t].z, g.z);
      float xa = fminf(a[t].w, g.w);
      float inter = fmaxf(ya - yi, 0.0f) * fmaxf(xa - xi, 0.0f);
      float Tj = areaA[t] + te;                 // S_j + EPS, one add
      // iou_j > iou_best  <=>  inter*T_best > num*T_j   (both T > 0)
      bool upd = inter * Tb[t] > num[t] * Tj;
      num[t]  = upd ? inter : num[t];
      Tb[t]   = upd ? Tj    : Tb[t];
      bidx[t] = upd ? j     : bidx[t];
    }
  }

  int npos = 0;
#pragma unroll
  for (int t = 0; t < APT; ++t) {
    const int i = base + t * BLK;
    // Exact reference rounding order for the pos test:
    // den = ((areaA + ga_best) - inter_best) + EPS ; iou = (10000*inter)/den
    const float gaB = garea[bidx[t]];
    const float den = ((areaA[t] + gaB) - num[t]) + 1e-5f;
    const float best_iou = (10000.0f * num[t]) / den;
    const bool pos = best_iou > 5000.0f;

    const float4 d = reinterpret_cast<const float4*>(deltas)[b * NAC + i];
    const float wb = a[t].w - a[t].y, hb = a[t].z - a[t].x;
    const float xc = a[t].y + 0.5f * wb + wb * d.x;
    const float yc = a[t].x + 0.5f * hb + hb * d.y;
    const float w_ = wb * __expf(d.z);
    const float h_ = hb * __expf(d.w);

    float* rowp = out + ((size_t)b * NAC + i) * 8;
    reinterpret_cast<float4*>(rowp)[0] =
        make_float4(yc - 0.5f * h_, xc - 0.5f * w_, yc + 0.5f * h_, xc + 0.5f * w_);
    if (USE_FLAGS) {
      reinterpret_cast<float4*>(rowp)[1] = make_float4(0.f, 0.f, 0.f, 0.f);
      flags[(size_t)b * NAC + i] = pos ? (unsigned char)(bidx[t] + 1) : 0u;
    } else {
      reinterpret_cast<float4*>(rowp)[1] =
          make_float4(pos ? (float)(bidx[t] + 1) : 0.0f, 0.f, 0.f, 0.f);
    }

    unsigned long long m = __ballot(pos);
    if ((tid & 63) == 0) npos += (int)__popcll(m);
  }
  if ((tid & 63) == 0 && npos)
    atomicAdd(&s_cnt, npos);
  __syncthreads();

  if (tid == 0) {
    if (USE_FLAGS) cnt_blk[b * GX + blockIdx.x] = s_cnt;  // written once, no memset
    else if (s_cnt) atomicAdd(&cnt_blk[b], s_cnt);
  }
}

// ---------------- Kernel 2a (flags): sum block counts, sparse sampling -------
__global__ __launch_bounds__(256) void k2_flags(
    const float* __restrict__ anchors,
    const float* __restrict__ gt,
    float* __restrict__ out,
    const int* __restrict__ cnt_blk,
    const unsigned char* __restrict__ flags,
    uint32_t kp0, uint32_t kp1)
{
  __shared__ int s_tot;
  const int b   = blockIdx.y;
  const int tid = threadIdx.x;

  if (tid == 0) s_tot = 0;
  __syncthreads();
  if (tid < GX) atomicAdd(&s_tot, cnt_blk[b * GX + tid]);
  __syncthreads();
  const float th = 128.0f / ((float)s_tot + 1e-6f);

  const int chunk = blockIdx.x * 256 + tid;   // 16 rows per thread
  uint4 fv = reinterpret_cast<const uint4*>(flags + (size_t)b * NAC)[chunk];
  if ((fv.x | fv.y | fv.z | fv.w) == 0u) return;

  const uint32_t words[4] = { fv.x, fv.y, fv.z, fv.w };
  const int base_i = chunk * 16;

#pragma unroll
  for (int w = 0; w < 4; ++w) {
    uint32_t wd = words[w];
    while (wd) {
      const int byte = __ffs(wd) / 8;        // flag <= 64 keeps byte MSB clear
      const int fl   = (wd >> (byte * 8)) & 0xFF;
      wd &= ~(0xFFu << (byte * 8));
      const int i = base_i + w * 4 + byte;
      const int f = b * NAC + i;

      uint32_t o0, o1;
      threefry2x32(kp0, kp1, 0u, (uint32_t)f, &o0, &o1);
      const uint32_t bits = o0 ^ o1;
      union { uint32_t u; float flt; } cv;
      cv.u = (bits >> 9) | 0x3F800000u;
      if (cv.flt - 1.0f < th) {
        const float4 a = reinterpret_cast<const float4*>(anchors)[i];
        const float4 g = reinterpret_cast<const float4*>(gt)[b * NGT + (fl - 1)];
        bbox2delta_store(a, g, out + (size_t)f * 8 + 4);
      }
    }
  }
}

// ---------------- Kernel 2b (fallback, proven): flag in out[4] ---------------
__global__ __launch_bounds__(256) void k2_fallback(
    const float* __restrict__ anchors,
    const float* __restrict__ gt,
    float* __restrict__ out,
    const int* __restrict__ counts,
    uint32_t kp0, uint32_t kp1)
{
  const int b = blockIdx.y;
  const int i = blockIdx.x * 256 + threadIdx.x;
  const int f = b * NAC + i;
  float* rowp = out + (size_t)f * 8;

  const float flag = rowp[4];
  if (flag == 0.0f) return;

  const float th = 128.0f / ((float)counts[b] + 1e-6f);

  uint32_t o0, o1;
  threefry2x32(kp0, kp1, 0u, (uint32_t)f, &o0, &o1);
  const uint32_t bits = o0 ^ o1;
  union { uint32_t u; float flt; } cv;
  cv.u = (bits >> 9) | 0x3F800000u;

  if (cv.flt - 1.0f < th) {
    const float4 a = reinterpret_cast<const float4*>(anchors)[i];
    const float4 g = reinterpret_cast<const float4*>(gt)[b * NGT + ((int)flag - 1)];
    bbox2delta_store(a, g, rowp + 4);
  } else {
    reinterpret_cast<float4*>(rowp)[1] = make_float4(0.f, 0.f, 0.f, 0.f);
  }
}

extern "C" void kernel_launch(void* const* d_in, const int* in_sizes, int n_in,
                              void* d_out, int out_size, void* d_ws, size_t ws_size,
                              hipStream_t stream)
{
  const float* anchors = (const float*)d_in[0];
  const float* gt      = (const float*)d_in[1];
  const float* deltas  = (const float*)d_in[2];
  float* out  = (float*)d_out;
  int* cnt_blk = (int*)d_ws;                                // [NB*GX] ints
  unsigned char* flags = (unsigned char*)d_ws + 8192;       // [NB*NAC] bytes

  const bool use_flags = ws_size >= (size_t)(8192 + NB * NAC);

  // kp = jax.random.split(jax.random.key(42))[0], threefry_partitionable:
  // kp = threefry2x32((0,42), 0, 0), full pair. (Verified rounds 2/3/5-9.)
  uint32_t kp0, kp1;
  threefry2x32(0u, 42u, 0u, 0u, &kp0, &kp1);

  dim3 g1(GX, NB);   // (192, 8) = 1536 blocks, 6/CU exact
  if (use_flags) {
    k1_classify<true><<<g1, dim3(BLK), 0, stream>>>(anchors, gt, deltas, out,
                                                    cnt_blk, flags);
    dim3 g2(NAC / 16 / 256, NB);   // (36, 8)
    k2_flags<<<g2, dim3(256), 0, stream>>>(anchors, gt, out, cnt_blk, flags,
                                           kp0, kp1);
  } else {
    hipMemsetAsync(cnt_blk, 0, NB * sizeof(int), stream);
    k1_classify<false><<<g1, dim3(BLK), 0, stream>>>(anchors, gt, deltas, out,
                                                     cnt_blk, nullptr);
    dim3 g2(NAC / 256, NB);        // (576, 8)
    k2_fallback<<<g2, dim3(256), 0, stream>>>(anchors, gt, out, cnt_blk,
                                              kp0, kp1);
  }
}

// Round 3
// 116.225 us; speedup vs baseline: 1.0190x; 1.0190x over previous
//
#include <hip/hip_runtime.h>
#include <stdint.h>

#define NAC 147456   // 128*128*9
#define NGT 64
#define NB  8
#define APT 3        // anchors per thread in k1 — measured optimum (round 8)
#define BLK 256
#define GX  (NAC / (BLK * APT))   // 192 -> grid 192x8 = 1536 blocks = 6/CU exact

// ---------------- Threefry-2x32 (JAX-compatible, 20 rounds) ----------------
__host__ __device__ static inline uint32_t tf_rotl(uint32_t x, uint32_t d) {
  return (x << d) | (x >> (32u - d));
}

__host__ __device__ static inline void threefry2x32(
    uint32_t k0, uint32_t k1, uint32_t x0, uint32_t x1,
    uint32_t* o0, uint32_t* o1)
{
  const uint32_t ks2 = k0 ^ k1 ^ 0x1BD11BDAu;
  x0 += k0; x1 += k1;
#define TFR(r) { x0 += x1; x1 = tf_rotl(x1, (r)); x1 ^= x0; }
  TFR(13u) TFR(15u) TFR(26u) TFR(6u)   x0 += k1;  x1 += ks2 + 1u;
  TFR(17u) TFR(29u) TFR(16u) TFR(24u)  x0 += ks2; x1 += k0 + 2u;
  TFR(13u) TFR(15u) TFR(26u) TFR(6u)   x0 += k0;  x1 += k1 + 3u;
  TFR(17u) TFR(29u) TFR(16u) TFR(24u)  x0 += k1;  x1 += ks2 + 4u;
  TFR(13u) TFR(15u) TFR(26u) TFR(6u)   x0 += ks2; x1 += k0 + 5u;
#undef TFR
  *o0 = x0; *o1 = x1;
}

__device__ static inline void bbox2delta_store(
    const float4& a, const float4& g, float* dst)
{
  const float wr  = a.w - a.y,          hr  = a.z - a.x;
  const float xcr = a.y + 0.5f * wr,    ycr = a.x + 0.5f * hr;
  const float wrc = fmaxf(wr, 1e-5f),   hrc = fmaxf(hr, 1e-5f);
  const float wl  = g.w - g.y,          hl  = g.z - g.x;
  const float xcl = g.y + 0.5f * wl,    ycl = g.x + 0.5f * hl;
  float4 r;
  r.x = fminf(fmaxf((xcl - xcr) / wrc, -10.0f), 10.0f);
  r.y = fminf(fmaxf((ycl - ycr) / hrc, -10.0f), 10.0f);
  r.z = fminf(fmaxf(__logf(wl / wrc),  -10.0f), 10.0f);
  r.w = fminf(fmaxf(__logf(hl / hrc),  -10.0f), 10.0f);
  *reinterpret_cast<float4*>(dst) = r;
}

// ---------------- Kernel 1: IoU argmax + proposals + flags + block count -----
// Round-12. History of the inner loop (counter-driven):
//   r10 div-free (num,den) in LDS-g form:        43.3us @ 81% VALUBusy
//   r11 T-form + SMEM g in loop:                 44.0us @ 72% busy  (NEUTRAL:
//       SMEM+DS share lgkmcnt, SMEM is out-of-order => compiler drains
//       lgkmcnt(0) before each consume; VALU savings eaten by stalls)
// r12 = T-form compare (keep) + g back in LDS (revert) + quad-prefetch of
// gae via one ds_read_b128 per 4-j group (5 DS ops/group vs 8; all group
// loads issued before any consume => single lgkmcnt covers the group).
//   compare: with S=areaA+ga, x=inter:
//     x_n/(S_n-x_n+e) > x_b/(S_b-x_b+e)  <=>  x_n*(S_b+e) > x_b*(S_n+e)
//   track (num, T=S+e); T_j = areaA + gae_j, gae = ga+EPS precomputed.
// pos threshold stays BIT-IDENTICAL to reference: epilogue recomputes
// den = ((areaA + garea[bidx]) - num) + e in reference rounding order,
// ONE IEEE div per anchor (3/thread).
// init (num=0, T=1): "update iff inter>0" first-iter semantics ==
// jnp.argmax first-max (all-zero-overlap anchors -> bidx=0).
// APT=3 => 1536 blocks = exactly 6 blocks/CU (uniform, no straggler tail).
// NO min-waves launch bound (round 7: register cap spills, +30MB scratch).
template <bool USE_FLAGS>
__global__ __launch_bounds__(BLK) void k1_classify(
    const float* __restrict__ anchors,
    const float* __restrict__ gt,
    const float* __restrict__ deltas,
    float* __restrict__ out,
    int* __restrict__ cnt_blk,          // USE_FLAGS: [NB*GX]; else counts[NB]
    unsigned char* __restrict__ flags)
{
  __shared__ __align__(16) float4 gbox[NGT];
  __shared__ __align__(16) float  garea[NGT];  // ga_j (exact, epilogue den)
  __shared__ __align__(16) float  gae[NGT];    // ga_j + EPS (T_j in compare)
  __shared__ int s_cnt;
  const int b   = blockIdx.y;
  const int tid = threadIdx.x;

  if (tid == 0) s_cnt = 0;
  if (tid < NGT) {
    float4 g = reinterpret_cast<const float4*>(gt)[b * NGT + tid];
    const float ga = fmaxf(g.z - g.x, 0.0f) * fmaxf(g.w - g.y, 0.0f);
    gbox[tid]  = g;
    garea[tid] = ga;
    gae[tid]   = ga + 1e-5f;
  }
  __syncthreads();

  const int base = blockIdx.x * (BLK * APT) + tid;

  float4 a[APT];
  float  areaA[APT], num[APT], Tb[APT];
  int    bidx[APT];
#pragma unroll
  for (int t = 0; t < APT; ++t) {
    a[t] = reinterpret_cast<const float4*>(anchors)[base + t * BLK];
    areaA[t] = fmaxf(a[t].z - a[t].x, 0.0f) * fmaxf(a[t].w - a[t].y, 0.0f);
    num[t]  = 0.0f;   // incumbent inter
    Tb[t]   = 1.0f;   // incumbent S+e; any >0 gives "update iff inter>0" init
    bidx[t] = 0;
  }

  for (int jj = 0; jj < NGT; jj += 4) {
    // One b128 for the 4 gae's + 4 broadcast b128 gbox reads, all issued
    // before any consume (one lgkmcnt wait per group).
    const float4 te4 = *reinterpret_cast<const float4*>(&gae[jj]);
    const float4 g0 = gbox[jj + 0];
    const float4 g1 = gbox[jj + 1];
    const float4 g2 = gbox[jj + 2];
    const float4 g3 = gbox[jj + 3];
    const float4 gs[4] = { g0, g1, g2, g3 };
#pragma unroll
    for (int u = 0; u < 4; ++u) {
      const float4 g  = gs[u];
      const float  te = (&te4.x)[u];   // static index after unroll
      const int    j  = jj + u;
#pragma unroll
      for (int t = 0; t < APT; ++t) {
        float yi = fmaxf(a[t].x, g.x);
        float xi = fmaxf(a[t].y, g.y);
        float ya = fminf(a[t].z, g.z);
        float xa = fminf(a[t].w, g.w);
        float inter = fmaxf(ya - yi, 0.0f) * fmaxf(xa - xi, 0.0f);
        float Tj = areaA[t] + te;                 // S_j + EPS, one add
        // iou_j > iou_best  <=>  inter*T_best > num*T_j   (both T > 0)
        bool upd = inter * Tb[t] > num[t] * Tj;
        num[t]  = upd ? inter : num[t];
        Tb[t]   = upd ? Tj    : Tb[t];
        bidx[t] = upd ? j     : bidx[t];
      }
    }
  }

  int npos = 0;
#pragma unroll
  for (int t = 0; t < APT; ++t) {
    const int i = base + t * BLK;
    // Exact reference rounding order for the pos test:
    // den = ((areaA + ga_best) - inter_best) + EPS ; iou = (10000*inter)/den
    const float gaB = garea[bidx[t]];
    const float den = ((areaA[t] + gaB) - num[t]) + 1e-5f;
    const float best_iou = (10000.0f * num[t]) / den;
    const bool pos = best_iou > 5000.0f;

    const float4 d = reinterpret_cast<const float4*>(deltas)[b * NAC + i];
    const float wb = a[t].w - a[t].y, hb = a[t].z - a[t].x;
    const float xc = a[t].y + 0.5f * wb + wb * d.x;
    const float yc = a[t].x + 0.5f * hb + hb * d.y;
    const float w_ = wb * __expf(d.z);
    const float h_ = hb * __expf(d.w);

    float* rowp = out + ((size_t)b * NAC + i) * 8;
    reinterpret_cast<float4*>(rowp)[0] =
        make_float4(yc - 0.5f * h_, xc - 0.5f * w_, yc + 0.5f * h_, xc + 0.5f * w_);
    if (USE_FLAGS) {
      reinterpret_cast<float4*>(rowp)[1] = make_float4(0.f, 0.f, 0.f, 0.f);
      flags[(size_t)b * NAC + i] = pos ? (unsigned char)(bidx[t] + 1) : 0u;
    } else {
      reinterpret_cast<float4*>(rowp)[1] =
          make_float4(pos ? (float)(bidx[t] + 1) : 0.0f, 0.f, 0.f, 0.f);
    }

    unsigned long long m = __ballot(pos);
    if ((tid & 63) == 0) npos += (int)__popcll(m);
  }
  if ((tid & 63) == 0 && npos)
    atomicAdd(&s_cnt, npos);
  __syncthreads();

  if (tid == 0) {
    if (USE_FLAGS) cnt_blk[b * GX + blockIdx.x] = s_cnt;  // written once, no memset
    else if (s_cnt) atomicAdd(&cnt_blk[b], s_cnt);
  }
}

// ---------------- Kernel 2a (flags): sum block counts, sparse sampling -------
__global__ __launch_bounds__(256) void k2_flags(
    const float* __restrict__ anchors,
    const float* __restrict__ gt,
    float* __restrict__ out,
    const int* __restrict__ cnt_blk,
    const unsigned char* __restrict__ flags,
    uint32_t kp0, uint32_t kp1)
{
  __shared__ int s_tot;
  const int b   = blockIdx.y;
  const int tid = threadIdx.x;

  if (tid == 0) s_tot = 0;
  __syncthreads();
  if (tid < GX) atomicAdd(&s_tot, cnt_blk[b * GX + tid]);
  __syncthreads();
  const float th = 128.0f / ((float)s_tot + 1e-6f);

  const int chunk = blockIdx.x * 256 + tid;   // 16 rows per thread
  uint4 fv = reinterpret_cast<const uint4*>(flags + (size_t)b * NAC)[chunk];
  if ((fv.x | fv.y | fv.z | fv.w) == 0u) return;

  const uint32_t words[4] = { fv.x, fv.y, fv.z, fv.w };
  const int base_i = chunk * 16;

#pragma unroll
  for (int w = 0; w < 4; ++w) {
    uint32_t wd = words[w];
    while (wd) {
      const int byte = __ffs(wd) / 8;        // flag <= 64 keeps byte MSB clear
      const int fl   = (wd >> (byte * 8)) & 0xFF;
      wd &= ~(0xFFu << (byte * 8));
      const int i = base_i + w * 4 + byte;
      const int f = b * NAC + i;

      uint32_t o0, o1;
      threefry2x32(kp0, kp1, 0u, (uint32_t)f, &o0, &o1);
      const uint32_t bits = o0 ^ o1;
      union { uint32_t u; float flt; } cv;
      cv.u = (bits >> 9) | 0x3F800000u;
      if (cv.flt - 1.0f < th) {
        const float4 a = reinterpret_cast<const float4*>(anchors)[i];
        const float4 g = reinterpret_cast<const float4*>(gt)[b * NGT + (fl - 1)];
        bbox2delta_store(a, g, out + (size_t)f * 8 + 4);
      }
    }
  }
}

// ---------------- Kernel 2b (fallback, proven): flag in out[4] ---------------
__global__ __launch_bounds__(256) void k2_fallback(
    const float* __restrict__ anchors,
    const float* __restrict__ gt,
    float* __restrict__ out,
    const int* __restrict__ counts,
    uint32_t kp0, uint32_t kp1)
{
  const int b = blockIdx.y;
  const int i = blockIdx.x * 256 + threadIdx.x;
  const int f = b * NAC + i;
  float* rowp = out + (size_t)f * 8;

  const float flag = rowp[4];
  if (flag == 0.0f) return;

  const float th = 128.0f / ((float)counts[b] + 1e-6f);

  uint32_t o0, o1;
  threefry2x32(kp0, kp1, 0u, (uint32_t)f, &o0, &o1);
  const uint32_t bits = o0 ^ o1;
  union { uint32_t u; float flt; } cv;
  cv.u = (bits >> 9) | 0x3F800000u;

  if (cv.flt - 1.0f < th) {
    const float4 a = reinterpret_cast<const float4*>(anchors)[i];
    const float4 g = reinterpret_cast<const float4*>(gt)[b * NGT + ((int)flag - 1)];
    bbox2delta_store(a, g, rowp + 4);
  } else {
    reinterpret_cast<float4*>(rowp)[1] = make_float4(0.f, 0.f, 0.f, 0.f);
  }
}

extern "C" void kernel_launch(void* const* d_in, const int* in_sizes, int n_in,
                              void* d_out, int out_size, void* d_ws, size_t ws_size,
                              hipStream_t stream)
{
  const float* anchors = (const float*)d_in[0];
  const float* gt      = (const float*)d_in[1];
  const float* deltas  = (const float*)d_in[2];
  float* out  = (float*)d_out;
  int* cnt_blk = (int*)d_ws;                                // [NB*GX] ints
  unsigned char* flags = (unsigned char*)d_ws + 8192;       // [NB*NAC] bytes

  const bool use_flags = ws_size >= (size_t)(8192 + NB * NAC);

  // kp = jax.random.split(jax.random.key(42))[0], threefry_partitionable:
  // kp = threefry2x32((0,42), 0, 0), full pair. (Verified rounds 2/3/5-9.)
  uint32_t kp0, kp1;
  threefry2x32(0u, 42u, 0u, 0u, &kp0, &kp1);

  dim3 g1(GX, NB);   // (192, 8) = 1536 blocks, 6/CU exact
  if (use_flags) {
    k1_classify<true><<<g1, dim3(BLK), 0, stream>>>(anchors, gt, deltas, out,
                                                    cnt_blk, flags);
    dim3 g2(NAC / 16 / 256, NB);   // (36, 8)
    k2_flags<<<g2, dim3(256), 0, stream>>>(anchors, gt, out, cnt_blk, flags,
                                           kp0, kp1);
  } else {
    hipMemsetAsync(cnt_blk, 0, NB * sizeof(int), stream);
    k1_classify<false><<<g1, dim3(BLK), 0, stream>>>(anchors, gt, deltas, out,
                                                     cnt_blk, nullptr);
    dim3 g2(NAC / 256, NB);        // (576, 8)
    k2_fallback<<<g2, dim3(256), 0, stream>>>(anchors, gt, out, cnt_blk,
                                              kp0, kp1);
  }
}